// Round 6
// baseline (13615.855 us; speedup 1.0000x reference)
//
#include <hip/hip_runtime.h>
#include <cstdint>

typedef float vf2 __attribute__((ext_vector_type(2)));

#define GB_M 128
#define GB_N 64
#define GB_K 16

// C[m,n] = act( sum_k A[row(m),k]*B[n,k] + bias[n] )
__global__ __launch_bounds__(256) void gemm_bt_f32(
    const float* __restrict__ A, const float* __restrict__ B,
    const float* __restrict__ bias, float* __restrict__ C,
    int Mc, int N, int K, int tc_shift, int Tfull, int t0, int act)
{
  __shared__ float As[GB_K][GB_M + 4];
  __shared__ float Bs[GB_K][GB_N + 4];
  const int tid = threadIdx.x;
  const int m0 = blockIdx.y * GB_M;
  const int n0 = blockIdx.x * GB_N;
  const int tx = tid & 15;
  const int ty = tid >> 4;

  const int tcmask = (1 << tc_shift) - 1;
  int arow[2];
#pragma unroll
  for (int i = 0; i < 2; i++) {
    int f = tid + i * 256;
    int row = f >> 2;
    int rc = m0 + row;
    arow[i] = (rc >> tc_shift) * Tfull + t0 + (rc & tcmask);
  }
  const int akq = tid & 3;
  const int brow = tid >> 2;
  const int bn = n0 + brow;

  vf2 acc2[4][4];
#pragma unroll
  for (int i = 0; i < 4; i++)
#pragma unroll
    for (int j = 0; j < 4; j++) acc2[i][j] = (vf2)(0.f);

  for (int k0 = 0; k0 < K; k0 += GB_K) {
#pragma unroll
    for (int i = 0; i < 2; i++) {
      int f = tid + i * 256;
      int row = f >> 2;
      float4 v = *(const float4*)(A + (size_t)arow[i] * K + k0 + akq * 4);
      As[akq * 4 + 0][row] = v.x; As[akq * 4 + 1][row] = v.y;
      As[akq * 4 + 2][row] = v.z; As[akq * 4 + 3][row] = v.w;
    }
    {
      float4 v = make_float4(0.f, 0.f, 0.f, 0.f);
      if (bn < N) v = *(const float4*)(B + (size_t)bn * K + k0 + akq * 4);
      Bs[akq * 4 + 0][brow] = v.x; Bs[akq * 4 + 1][brow] = v.y;
      Bs[akq * 4 + 2][brow] = v.z; Bs[akq * 4 + 3][brow] = v.w;
    }
    __syncthreads();
#pragma unroll
    for (int k = 0; k < GB_K; k++) {
      float4 a0 = *(const float4*)&As[k][ty * 8];
      float4 a1 = *(const float4*)&As[k][ty * 8 + 4];
      float4 b0 = *(const float4*)&Bs[k][tx * 4];
      vf2 a2[4];
      a2[0] = (vf2){a0.x, a0.y}; a2[1] = (vf2){a0.z, a0.w};
      a2[2] = (vf2){a1.x, a1.y}; a2[3] = (vf2){a1.z, a1.w};
      float bv[4] = {b0.x, b0.y, b0.z, b0.w};
#pragma unroll
      for (int j = 0; j < 4; j++) {
        vf2 bs = (vf2){bv[j], bv[j]};
#pragma unroll
        for (int ip = 0; ip < 4; ip++)
          acc2[ip][j] = __builtin_elementwise_fma(a2[ip], bs, acc2[ip][j]);
      }
    }
    __syncthreads();
  }

#pragma unroll
  for (int j = 0; j < 4; j++) {
    int n = n0 + tx * 4 + j;
    if (n >= N) continue;
    float bz = bias[n];
#pragma unroll
    for (int i = 0; i < 8; i++) {
      int m = m0 + ty * 8 + i;
      float x = ((i & 1) ? acc2[i >> 1][j].y : acc2[i >> 1][j].x) + bz;
      if (act == 1) {
        x = 1.0507009873554805f * (x > 0.f ? x : 1.6732632423543772f * (__expf(x) - 1.f));
      } else if (act == 2) {
        x = tanhf(x);
      }
      C[(size_t)m * N + n] = x;
    }
  }
}

#define RT 512
#define RNWG 256

__device__ __forceinline__ void pollge(const unsigned* fp, unsigned want) {
  while (__hip_atomic_load(fp, __ATOMIC_RELAXED, __HIP_MEMORY_SCOPE_AGENT) < want)
    __builtin_amdgcn_s_sleep(1);
}

// Persistent GRU recurrence, round-10: WAVE-SPECIALIZED PIPELINE.
// 512 threads: waves 0-5 compute half-round r from LDS buf[r&1]; waves 6-7
// concurrently poll flag(r+1) + stage next half's h into buf[(r+1)&1].
// One barrier per half-round (2/step, unchanged). Flag semantics, hb parity
// ping-pong, publish-after-barrier-drain all identical to the proven r9
// protocol; the only change is WHO stages and WHEN (overlapped, 1-round lag).
// Round r: tt = t0 + (r>>1), half = r&1 (0=X batches 8sd..+3, 1=Y +4..+7).
// Publish at round start: half==0 -> flagY(tt) (data drained at BAR(r-1));
// half==1 -> flagX(tt+1). Staging in round r: half (r+1)&1 of step
// t0+((r+1)>>1), polls exactly ONE flag per staging thread.
__global__ __launch_bounds__(RT, 1) void gru_rec(
    const float* __restrict__ gi, const float* __restrict__ w_hh,
    const float* __restrict__ b_hh, float* __restrict__ hb,
    unsigned* __restrict__ flags, float* __restrict__ seq,
    int t0, int Tc)
{
  __shared__ float buf[2][4][776];   // [round parity][batch-in-half][dim]
  const int wg = blockIdx.x;
  const int jg = wg & 63;
  const int sd = wg >> 6;
  const int j0 = jg * 12;
  const int tid = threadIdx.x;
  const int p  = tid >> 6;            // wave 0..7
  const int pp = (p <= 5) ? p : p - 6;  // clamp for staging waves (avoid OOB)
  const int ks = tid & 63;

  unsigned* flagX_my = flags + (((0 * 4 + sd) * 64) + jg) * 16;
  unsigned* flagY_my = flags + (((1 * 4 + sd) * 64) + jg) * 16;

  // ---- compute-wave setup (wreg valid/meaningful for waves 0-5) ----
  float4 wreg[3][2][3];
#pragma unroll
  for (int g = 0; g < 3; g++)
#pragma unroll
    for (int j2 = 0; j2 < 2; j2++)
#pragma unroll
      for (int kk = 0; kk < 3; kk++)
        wreg[g][j2][kk] = *(const float4*)(
            w_hh + (size_t)(g * 768 + j0 + 2 * pp + j2) * 768 + (kk * 64 + ks) * 4);

  const int j2l = (ks >> 2) & 1;
  const int cl  = ks & 3;
  const int j_out = j0 + 2 * pp + j2l;
  const float bhr = b_hh[j_out];
  const float bhz = b_hh[768 + j_out];
  const float bhn = b_hh[1536 + j_out];

  const bool hi4 = (ks & 4) != 0;
  const bool hi2 = (ks & 2) != 0;
  const bool hi1 = (ks & 1) != 0;

  // ---- staging-wave setup (waves 6-7): 128 threads, 2 batches x 12 dims each
  const int su    = (tid - 384) & 127;   // 0..127 (garbage-masked for tid<384)
  const int jgx   = su & 63;             // flag index / dim group
  const int pairb = su >> 6;             // 0..1 -> batches 2pairb, 2pairb+1
  const unsigned* fX_st = flags + (((0 * 4 + sd) * 64) + jgx) * 16;
  const unsigned* fY_st = flags + (((1 * 4 + sd) * 64) + jgx) * 16;

  auto stage_half = [&](int ts, int hhalf, int bsel) {
    pollge(hhalf ? fY_st : fX_st, (unsigned)ts);
    const float* base = hb + (size_t)(ts & 1) * 24576
        + (size_t)(8 * sd + 4 * hhalf + 2 * pairb) * 768 + 12 * jgx;
    const unsigned long long* s0 = (const unsigned long long*)base;
    const unsigned long long* s1 = (const unsigned long long*)(base + 768);
    unsigned long long v[12];
#pragma unroll
    for (int i = 0; i < 6; i++)
      v[i] = __hip_atomic_load(s0 + i, __ATOMIC_RELAXED, __HIP_MEMORY_SCOPE_AGENT);
#pragma unroll
    for (int i = 0; i < 6; i++)
      v[6 + i] = __hip_atomic_load(s1 + i, __ATOMIC_RELAXED, __HIP_MEMORY_SCOPE_AGENT);
    float* d0 = &buf[bsel][2 * pairb][12 * jgx];
    float* d1 = &buf[bsel][2 * pairb + 1][12 * jgx];
#pragma unroll
    for (int q = 0; q < 3; q++) {
      *(float4*)(d0 + 4 * q) = make_float4(
          __uint_as_float((unsigned)v[2 * q]),
          __uint_as_float((unsigned)(v[2 * q] >> 32)),
          __uint_as_float((unsigned)v[2 * q + 1]),
          __uint_as_float((unsigned)(v[2 * q + 1] >> 32)));
      *(float4*)(d1 + 4 * q) = make_float4(
          __uint_as_float((unsigned)v[6 + 2 * q]),
          __uint_as_float((unsigned)(v[6 + 2 * q] >> 32)),
          __uint_as_float((unsigned)v[6 + 2 * q + 1]),
          __uint_as_float((unsigned)(v[6 + 2 * q + 1] >> 32)));
    }
  };

  // prologue: stage X(t0) into buf[0] (flagX(t0) from prev chunk / memset)
  if (tid >= 384) stage_half(t0, 0, 0);
  __syncthreads();

  const int nr = 2 * Tc;
  for (int r = 0; r < nr; r++) {
    const int q  = r >> 1;
    const int tt = t0 + q;
    const int half = r & 1;

    // publish: the data produced in round r-1 drained at BAR(r-1)
    if (tid == 0) {
      if (half == 0)
        __hip_atomic_store(flagY_my, (unsigned)tt, __ATOMIC_RELAXED, __HIP_MEMORY_SCOPE_AGENT);
      else
        __hip_atomic_store(flagX_my, (unsigned)(tt + 1), __ATOMIC_RELAXED, __HIP_MEMORY_SCOPE_AGENT);
    }

    if (tid < 384) {
      // ---------------- compute waves: this half's 4 batches ----------------
      const int b_out = 8 * sd + 4 * half + cl;
      float gr = 0.f, gz = 0.f, gn = 0.f;
      if (ks < 8) {
        const float* g = gi + ((size_t)b_out * Tc + q) * 2304 + j_out;
        gr = g[0]; gz = g[768]; gn = g[1536];
      }

      vf2 a2[3][2][4];
#pragma unroll
      for (int g = 0; g < 3; g++)
#pragma unroll
        for (int j2 = 0; j2 < 2; j2++)
#pragma unroll
          for (int c = 0; c < 4; c++) a2[g][j2][c] = (vf2)(0.f);
#pragma unroll
      for (int kk = 0; kk < 3; kk++) {
        const int off = (kk * 64 + ks) * 4;
        vf2 hlo[4], hhi[4];
#pragma unroll
        for (int c = 0; c < 4; c++) {
          float4 h = *(const float4*)(&buf[half][c][0] + off);
          hlo[c] = (vf2){h.x, h.y};
          hhi[c] = (vf2){h.z, h.w};
        }
#pragma unroll
        for (int g = 0; g < 3; g++)
#pragma unroll
          for (int j2 = 0; j2 < 2; j2++) {
            float4 w = wreg[g][j2][kk];
            vf2 wlo = (vf2){w.x, w.y};
            vf2 whi = (vf2){w.z, w.w};
#pragma unroll
            for (int c = 0; c < 4; c++) {
              a2[g][j2][c] = __builtin_elementwise_fma(wlo, hlo[c], a2[g][j2][c]);
              a2[g][j2][c] = __builtin_elementwise_fma(whi, hhi[c], a2[g][j2][c]);
            }
          }
      }
      float acc[3][2][4];
#pragma unroll
      for (int g = 0; g < 3; g++)
#pragma unroll
        for (int j2 = 0; j2 < 2; j2++)
#pragma unroll
          for (int c = 0; c < 4; c++) acc[g][j2][c] = a2[g][j2][c].x + a2[g][j2][c].y;

      float r12[3][4];
#pragma unroll
      for (int g = 0; g < 3; g++)
#pragma unroll
        for (int c = 0; c < 4; c++) {
          float send = hi4 ? acc[g][0][c] : acc[g][1][c];
          float keep = hi4 ? acc[g][1][c] : acc[g][0][c];
          r12[g][c] = keep + __shfl_xor(send, 4);
        }
      float r6[3][2];
#pragma unroll
      for (int g = 0; g < 3; g++)
#pragma unroll
        for (int c2 = 0; c2 < 2; c2++) {
          float send = hi2 ? r12[g][c2] : r12[g][2 + c2];
          float keep = hi2 ? r12[g][2 + c2] : r12[g][c2];
          r6[g][c2] = keep + __shfl_xor(send, 2);
        }
      float r3[3];
#pragma unroll
      for (int g = 0; g < 3; g++) {
        float send = hi1 ? r6[g][0] : r6[g][1];
        float keep = hi1 ? r6[g][1] : r6[g][0];
        r3[g] = keep + __shfl_xor(send, 1);
      }
#pragma unroll
      for (int g = 0; g < 3; g++) {
        r3[g] += __shfl_xor(r3[g], 8);
        r3[g] += __shfl_xor(r3[g], 16);
        r3[g] += __shfl_xor(r3[g], 32);
      }

      if (ks < 8) {
        float hp = buf[half][cl][j_out];
        float rg = 1.f / (1.f + __expf(-(gr + r3[0] + bhr)));
        float zg = 1.f / (1.f + __expf(-(gz + r3[1] + bhz)));
        float ng = tanhf(gn + rg * (r3[2] + bhn));
        float hv = (1.f - zg) * ng + zg * hp;
        __hip_atomic_store(hb + (size_t)((tt + 1) & 1) * 24576 + (size_t)b_out * 768 + j_out,
                           hv, __ATOMIC_RELAXED, __HIP_MEMORY_SCOPE_AGENT);
        seq[((size_t)b_out * 1024 + tt) * 768 + j_out] = hv;
      }
    } else if (r + 1 < nr) {
      // ---------------- staging waves: next half into buf[(r+1)&1] ----------
      const int rs = r + 1;
      stage_half(t0 + (rs >> 1), rs & 1, rs & 1);
    }
    __syncthreads();   // BAR(r): drains hv stores; syncs buf[(r+1)&1]
  }
  // tail: h_Y(t0+Tc) stores drained at the loop's final barrier
  if (tid == 0)
    __hip_atomic_store(flagY_my, (unsigned)(t0 + Tc), __ATOMIC_RELAXED, __HIP_MEMORY_SCOPE_AGENT);
}

extern "C" void kernel_launch(void* const* d_in, const int* in_sizes, int n_in,
                              void* d_out, int out_size, void* d_ws, size_t ws_size,
                              hipStream_t stream) {
  const float* feat  = (const float*)d_in[0];
  const float* w_ih0 = (const float*)d_in[2];
  const float* w_hh0 = (const float*)d_in[3];
  const float* b_ih0 = (const float*)d_in[4];
  const float* b_hh0 = (const float*)d_in[5];
  const float* w_ih1 = (const float*)d_in[6];
  const float* w_hh1 = (const float*)d_in[7];
  const float* b_ih1 = (const float*)d_in[8];
  const float* b_hh1 = (const float*)d_in[9];
  const float* fc_w  = (const float*)d_in[10];
  const float* fc_b  = (const float*)d_in[11];
  const float* out_w = (const float*)d_in[12];
  const float* out_b = (const float*)d_in[13];
  float* out = (float*)d_out;

  const int Tc = 256;
  const int McChunk = 32 * Tc;

  float* proj = (float*)d_ws;                               // 18,874,368 f
  float* seq  = proj + (size_t)32 * Tc * 2304;              // 25,165,824 f
  float* hbuf = seq + (size_t)25165824;                     // 2*24576 f
  unsigned* flags = (unsigned*)(hbuf + 2 * 24576);          // 2 x 4 x 64 x 64B = 32 KB

  // ---- layer 0 ----
  hipMemsetAsync(hbuf, 0, 2 * 24576 * sizeof(float), stream);
  hipMemsetAsync(flags, 0, 32768, stream);
  for (int c = 0; c < 4; c++) {
    gemm_bt_f32<<<dim3(36, McChunk / 128), dim3(256), 0, stream>>>(
        feat, w_ih0, b_ih0, proj, McChunk, 2304, 768, 8, 1024, c * Tc, 0);
    gru_rec<<<dim3(RNWG), dim3(RT), 0, stream>>>(
        proj, w_hh0, b_hh0, hbuf, flags, seq, c * Tc, Tc);
  }
  // ---- layer 1 ----
  hipMemsetAsync(hbuf, 0, 2 * 24576 * sizeof(float), stream);
  hipMemsetAsync(flags, 0, 32768, stream);
  for (int c = 0; c < 4; c++) {
    gemm_bt_f32<<<dim3(36, McChunk / 128), dim3(256), 0, stream>>>(
        seq, w_ih1, b_ih1, proj, McChunk, 2304, 768, 8, 1024, c * Tc, 0);
    gru_rec<<<dim3(RNWG), dim3(RT), 0, stream>>>(
        proj, w_hh1, b_hh1, hbuf, flags, seq, c * Tc, Tc);
  }
  // ---- fc + SELU ----
  gemm_bt_f32<<<dim3(8, 256), dim3(256), 0, stream>>>(
      seq, fc_w, fc_b, proj, 32768, 512, 768, 15, 32768, 0, 1);
  // ---- out + tanh ----
  gemm_bt_f32<<<dim3(1, 256), dim3(256), 0, stream>>>(
      proj, out_w, out_b, out, 32768, 39, 512, 15, 32768, 0, 2);
}